// Round 16
// baseline (2265.549 us; speedup 1.0000x reference)
//
#include <hip/hip_runtime.h>
#include <limits.h>

#define CDIM 256
#define KDIM 8192
#define NROWS 32768
#define THW 8192
#define BNQ 64
#define BNR 32       // full-resolve rows per block
#define NPAN 4       // code panels (2048 codes each; W-panel 2MB stays in L2)
#define WSIG 8.0e-5f // certified sigma window

typedef __attribute__((ext_vector_type(8))) short short8v;
typedef __attribute__((ext_vector_type(8))) unsigned short u16x8;
typedef __attribute__((ext_vector_type(4))) float f32x4;
typedef __attribute__((ext_vector_type(4))) unsigned short u16x4;

__device__ __forceinline__ float sq_rn(float a) { return __fmul_rn(a, a); }
__device__ __forceinline__ unsigned short bf16rn(float x) {
    unsigned u = __float_as_uint(x);
    return (unsigned short)((u + 0x7FFFu + ((u >> 16) & 1u)) >> 16);
}
__device__ __forceinline__ float bf16tof(unsigned short h) {
    return __uint_as_float(((unsigned)h) << 16);
}

// merge top-3 quintuple (rank-1 tie -> lower k; fixed order => deterministic)
__device__ __forceinline__ void merge3(float& m1, int& i1, float& m2, int& i2,
                                       float& m3, float om1, int oi1,
                                       float om2, int oi2, float om3) {
    if (om1 < m1 || (om1 == m1 && oi1 < i1)) {
        float n2; int n2i;
        if (m1 < om2 || (m1 == om2 && i1 < oi2)) { n2 = m1; n2i = i1; m3 = fminf(m2, om2); }
        else { n2 = om2; n2i = oi2; m3 = fminf(m1, om3); }
        m2 = n2; i2 = n2i; m1 = om1; i1 = oi1;
    } else {
        if (om1 < m2 || (om1 == m2 && oi1 < i2)) { m3 = fminf(m2, om2); m2 = om1; i2 = oi1; }
        else { m3 = fminf(m3, om1); }
    }
}

// numpy pairwise sum of 128 fp32 squares, AVX512 model (verified round 3).
__device__ float pairwise128_sq(const float* __restrict__ p, int stride) {
    float s[16];
#pragma unroll
    for (int l = 0; l < 16; ++l) {
        const float a0 = sq_rn(p[(l)*stride]);
        const float a1 = sq_rn(p[(16 + l) * stride]);
        const float a2 = sq_rn(p[(32 + l) * stride]);
        const float a3 = sq_rn(p[(48 + l) * stride]);
        const float a4 = sq_rn(p[(64 + l) * stride]);
        const float a5 = sq_rn(p[(80 + l) * stride]);
        const float a6 = sq_rn(p[(96 + l) * stride]);
        const float a7 = sq_rn(p[(112 + l) * stride]);
        s[l] = __fadd_rn(__fadd_rn(__fadd_rn(a0, a1), __fadd_rn(a2, a3)),
                         __fadd_rn(__fadd_rn(a4, a5), __fadd_rn(a6, a7)));
    }
    const float u0 = __fadd_rn(__fadd_rn(s[0], s[8]),  __fadd_rn(s[4], s[12]));
    const float u1 = __fadd_rn(__fadd_rn(s[1], s[9]),  __fadd_rn(s[5], s[13]));
    const float u2 = __fadd_rn(__fadd_rn(s[2], s[10]), __fadd_rn(s[6], s[14]));
    const float u3 = __fadd_rn(__fadd_rn(s[3], s[11]), __fadd_rn(s[7], s[15]));
    return __fadd_rn(__fadd_rn(u0, u2), __fadd_rn(u1, u3));
}

__global__ __launch_bounds__(256) void k_A(const float* __restrict__ z,
                                           float* __restrict__ A) {
    const int n = blockIdx.x * 256 + threadIdx.x;
    const float* zp = z + (size_t)(n >> 13) * (CDIM * THW) + (n & (THW - 1));
    const float b0 = pairwise128_sq(zp, THW);
    const float b1 = pairwise128_sq(zp + (size_t)128 * THW, THW);
    A[n] = __fadd_rn(b0, b1);
}

__global__ __launch_bounds__(256) void k_C(const float* __restrict__ w,
                                           float* __restrict__ Cq) {
    const int k = blockIdx.x * 256 + threadIdx.x;
    const float* wp = w + (size_t)k * CDIM;
    Cq[k] = __fadd_rn(pairwise128_sq(wp, 1), pairwise128_sq(wp + 128, 1));
}

__global__ __launch_bounds__(256) void k_split(const float* __restrict__ w,
                                               unsigned short* __restrict__ W1,
                                               unsigned short* __restrict__ W2) {
    const int i = blockIdx.x * 256 + threadIdx.x;
    float4 v = *reinterpret_cast<const float4*>(w + (size_t)i * 4);
    const float x[4] = {v.x, v.y, v.z, v.w};
    u16x4 h, lo;
#pragma unroll
    for (int q = 0; q < 4; ++q) {
        const unsigned short hh = bf16rn(x[q]);
        h[q] = hh;
        lo[q] = bf16rn(x[q] - bf16tof(hh));
    }
    *reinterpret_cast<u16x4*>(W1 + (size_t)i * 4) = h;
    *reinterpret_cast<u16x4*>(W2 + (size_t)i * 4) = lo;
}

// Panel-tiled MFMA split-bf16 filter. z staged via NON-TEMPORAL loads (z never
// enters L2 -> W panel stays resident) + vector ds_write_b128 staging with
// (n&31) XOR swizzle (write ~conflict-free; read 2-way-free, same swizzle).
__global__ __launch_bounds__(256, 2) void k_filter(
    const float* __restrict__ z,
    const unsigned short* __restrict__ W1, const unsigned short* __restrict__ W2,
    const float* __restrict__ Cq,
    float* __restrict__ pm1, int* __restrict__ pi1,
    float* __restrict__ pm2, int* __restrict__ pi2, float* __restrict__ pm3)
{
    __shared__ unsigned short Z1t[64 * 256];  // 32 KB swizzled bf16 hi
    __shared__ unsigned short Z2t[64 * 256];  // 32 KB lo
    __shared__ float wm1[4][64], wm2[4][64], wm3[4][64];
    __shared__ int   wi1[4][64], wi2[4][64];

    const int t = threadIdx.x;
    const int blk = blockIdx.x;
    const int p = blk >> 9;          // panel (panel-major => co-resident share)
    const int rtile = blk & 511;     // row tile
    const int n0 = rtile * 64;
    const int b = n0 >> 13;
    const int s0 = n0 & (THW - 1);
    const float* zb = z + (size_t)b * (CDIM * THW) + s0;

    {   // stage + split z: nt loads (bypass L2), one row per lane, 8-c runs,
        // vector b128 writes at n*512 + ((c*2) ^ ((n&31)<<4))
        const int lane = t & 63;
        const int cg = t >> 6;
        const float* zcol = zb + lane;
        const int swz = (lane & 31) << 4;
#pragma unroll
        for (int it = 0; it < 8; ++it) {
            const int c0 = cg * 8 + it * 32;
            u16x8 hi, lo;
#pragma unroll
            for (int j = 0; j < 8; ++j) {
                const float v = __builtin_nontemporal_load(zcol + (size_t)(c0 + j) * THW);
                const unsigned short h = bf16rn(v);
                hi[j] = h;
                lo[j] = bf16rn(v - bf16tof(h));
            }
            const int off = lane * 512 + ((c0 * 2) ^ swz);
            *(u16x8*)((char*)Z1t + off) = hi;
            *(u16x8*)((char*)Z2t + off) = lo;
        }
    }
    __syncthreads();

    const int l = t & 63;
    const int wv = t >> 6;
    const int l15 = l & 15;
    const int lg = l >> 4;
    const int stripe = p * 2048 + wv * 512;

    float m1v[4][4], m2v[4][4], m3v[4][4];
    int i1v[4][4], i2v[4][4];
#pragma unroll
    for (int rt = 0; rt < 4; ++rt)
#pragma unroll
        for (int i = 0; i < 4; ++i) {
            m1v[rt][i] = 3.0e38f; m2v[rt][i] = 3.0e38f; m3v[rt][i] = 3.0e38f;
            i1v[rt][i] = INT_MAX; i2v[rt][i] = INT_MAX;
        }

    for (int st = 0; st < 8; ++st) {
        const int kb = stripe + st * 64;
        f32x4 acc[4][4];
#pragma unroll
        for (int rt = 0; rt < 4; ++rt)
#pragma unroll
            for (int ct = 0; ct < 4; ++ct)
                acc[rt][ct] = (f32x4){0.f, 0.f, 0.f, 0.f};

        float cqv[4];
#pragma unroll
        for (int ct = 0; ct < 4; ++ct) cqv[ct] = Cq[kb + ct * 16 + l15];

#pragma unroll
        for (int ks = 0; ks < 8; ++ks) {
            const int cb = ks * 32 + lg * 8;
            short8v a1[4], a2[4], bb1[4], bb2[4];
#pragma unroll
            for (int rt = 0; rt < 4; ++rt) {
                const int n = rt * 16 + l15;
                const int off = n * 512 + ((cb * 2) ^ ((n & 31) << 4));
                a1[rt] = *(const short8v*)((const char*)Z1t + off);
                a2[rt] = *(const short8v*)((const char*)Z2t + off);
            }
#pragma unroll
            for (int ct = 0; ct < 4; ++ct) {
                const size_t wo = (size_t)(kb + ct * 16 + l15) * CDIM + cb;
                bb1[ct] = *reinterpret_cast<const short8v*>(W1 + wo);
                bb2[ct] = *reinterpret_cast<const short8v*>(W2 + wo);
            }
#pragma unroll
            for (int rt = 0; rt < 4; ++rt)
#pragma unroll
                for (int ct = 0; ct < 4; ++ct) {
                    acc[rt][ct] = __builtin_amdgcn_mfma_f32_16x16x32_bf16(a1[rt], bb1[ct], acc[rt][ct], 0, 0, 0);
                    acc[rt][ct] = __builtin_amdgcn_mfma_f32_16x16x32_bf16(a1[rt], bb2[ct], acc[rt][ct], 0, 0, 0);
                    acc[rt][ct] = __builtin_amdgcn_mfma_f32_16x16x32_bf16(a2[rt], bb1[ct], acc[rt][ct], 0, 0, 0);
                }
        }

        // sigma = Cq - 2*dot; running top-3 per row; ct/st ascending = k asc.
#pragma unroll
        for (int rt = 0; rt < 4; ++rt)
#pragma unroll
            for (int i = 0; i < 4; ++i) {
#pragma unroll
                for (int ct = 0; ct < 4; ++ct) {
                    const float sig = fmaf(-2.0f, acc[rt][ct][i], cqv[ct]);
                    const int kg = kb + ct * 16 + l15;
                    if (sig < m3v[rt][i]) {
                        if (sig < m1v[rt][i] || (sig == m1v[rt][i] && kg < i1v[rt][i])) {
                            m3v[rt][i] = m2v[rt][i]; m2v[rt][i] = m1v[rt][i]; i2v[rt][i] = i1v[rt][i];
                            m1v[rt][i] = sig; i1v[rt][i] = kg;
                        } else if (sig < m2v[rt][i]) {
                            m3v[rt][i] = m2v[rt][i]; m2v[rt][i] = sig; i2v[rt][i] = kg;
                        } else {
                            m3v[rt][i] = sig;
                        }
                    }
                }
            }
    }

    // merge across the 16 l15 lanes of each lg group
#pragma unroll
    for (int mm = 1; mm < 16; mm <<= 1) {
#pragma unroll
        for (int rt = 0; rt < 4; ++rt)
#pragma unroll
            for (int i = 0; i < 4; ++i) {
                const float om1 = __shfl_xor(m1v[rt][i], mm, 64);
                const int oi1 = __shfl_xor(i1v[rt][i], mm, 64);
                const float om2 = __shfl_xor(m2v[rt][i], mm, 64);
                const int oi2 = __shfl_xor(i2v[rt][i], mm, 64);
                const float om3 = __shfl_xor(m3v[rt][i], mm, 64);
                merge3(m1v[rt][i], i1v[rt][i], m2v[rt][i], i2v[rt][i], m3v[rt][i],
                       om1, oi1, om2, oi2, om3);
            }
    }
    if (l15 == 0) {
#pragma unroll
        for (int rt = 0; rt < 4; ++rt)
#pragma unroll
            for (int i = 0; i < 4; ++i) {
                const int row = rt * 16 + lg * 4 + i;
                wm1[wv][row] = m1v[rt][i]; wi1[wv][row] = i1v[rt][i];
                wm2[wv][row] = m2v[rt][i]; wi2[wv][row] = i2v[rt][i];
                wm3[wv][row] = m3v[rt][i];
            }
    }
    __syncthreads();

    if (t < 64) {   // merge 4 wave-stripes (ascending k), write panel partials
        float m1 = 3.0e38f, m2 = 3.0e38f, m3 = 3.0e38f;
        int i1 = INT_MAX, i2 = INT_MAX;
#pragma unroll
        for (int v = 0; v < 4; ++v)
            merge3(m1, i1, m2, i2, m3, wm1[v][t], wi1[v][t], wm2[v][t], wi2[v][t], wm3[v][t]);
        const int g = p * NROWS + n0 + t;
        pm1[g] = m1; pi1[g] = i1; pm2[g] = m2; pi2[g] = i2; pm3[g] = m3;
    }
}

// Merge the 4 panel partials per row; emit idx, pair candidate, flag3, counts.
__global__ __launch_bounds__(256) void k_merge(
    const float* __restrict__ pm1, const int* __restrict__ pi1,
    const float* __restrict__ pm2, const int* __restrict__ pi2,
    const float* __restrict__ pm3,
    float* __restrict__ idx_f, int* __restrict__ pairs,
    int* __restrict__ flag3, int* __restrict__ cnt64)
{
    const int n = blockIdx.x * 256 + threadIdx.x;
    float m1 = 3.0e38f, m2 = 3.0e38f, m3 = 3.0e38f;
    int i1 = INT_MAX, i2 = INT_MAX;
#pragma unroll
    for (int p = 0; p < NPAN; ++p) {
        const int g = p * NROWS + n;
        merge3(m1, i1, m2, i2, m3, pm1[g], pi1[g], pm2[g], pi2[g], pm3[g]);
    }
    idx_f[n] = (float)i1;
    const int f3 = (m3 - m1 <= WSIG) ? 1 : 0;
    const int f2 = (!f3 && (m2 - m1 <= WSIG)) ? 1 : 0;
    pairs[n] = f2 ? i2 : -1;
    flag3[n] = f3;
    const unsigned long long msk = __ballot(f3);
    if ((threadIdx.x & 63) == 0) cnt64[n >> 6] = (int)__popcll(msk);
}

// np-exact pair resolve: d for {i1, i2} only (single ascending-c fmaf chain).
__global__ __launch_bounds__(256) void k_pair(
    const float* __restrict__ z, const float* __restrict__ w,
    const float* __restrict__ A, const float* __restrict__ Cq,
    const int* __restrict__ pairs, float* __restrict__ idx_f)
{
    const int n = blockIdx.x * 256 + threadIdx.x;
    const int i2 = pairs[n];
    if (i2 < 0) return;
    const int i1 = (int)idx_f[n];
    const float* zp = z + (size_t)(n >> 13) * (CDIM * THW) + (n & (THW - 1));
    const float An = A[n];
    float ma = 0.f, mb = 0.f;
    const float4* wa = (const float4*)(w + (size_t)i1 * CDIM);
    const float4* wb = (const float4*)(w + (size_t)i2 * CDIM);
#pragma unroll 4
    for (int c4 = 0; c4 < CDIM / 4; ++c4) {
        const float z0 = zp[(size_t)(c4 * 4 + 0) * THW];
        const float z1 = zp[(size_t)(c4 * 4 + 1) * THW];
        const float z2 = zp[(size_t)(c4 * 4 + 2) * THW];
        const float z3 = zp[(size_t)(c4 * 4 + 3) * THW];
        const float4 va = wa[c4], vb = wb[c4];
        ma = fmaf(z0, va.x, ma); ma = fmaf(z1, va.y, ma);
        ma = fmaf(z2, va.z, ma); ma = fmaf(z3, va.w, ma);
        mb = fmaf(z0, vb.x, mb); mb = fmaf(z1, vb.y, mb);
        mb = fmaf(z2, vb.z, mb); mb = fmaf(z3, vb.w, mb);
    }
    const float d1 = __fadd_rn(__fadd_rn(An, -2.0f * ma), Cq[i1]);
    const float d2 = __fadd_rn(__fadd_rn(An, -2.0f * mb), Cq[i2]);
    int win = i1;
    if (d2 < d1 || (d2 == d1 && i2 < i1)) win = i2;
    idx_f[n] = (float)win;
}

__global__ __launch_bounds__(512) void k_scan(const int* __restrict__ cnt64,
                                              int* __restrict__ off,
                                              int* __restrict__ nf) {
    __shared__ int sh[512];
    const int t = threadIdx.x;
    const int c = cnt64[t];
    sh[t] = c;
    __syncthreads();
    for (int o = 1; o < 512; o <<= 1) {
        const int v = (t >= o) ? sh[t - o] : 0;
        __syncthreads();
        sh[t] += v;
        __syncthreads();
    }
    off[t] = sh[t] - c;
    if (t == 511) nf[0] = sh[511];
}

__global__ __launch_bounds__(64) void k_scatter(const int* __restrict__ flag,
                                                const int* __restrict__ off,
                                                int* __restrict__ wlist) {
    const int t = threadIdx.x;
    const int n = blockIdx.x * 64 + t;
    const int flg = flag[n];
    const unsigned long long msk = __ballot(flg);
    const int pre = (int)__popcll(msk & ((1ull << t) - 1ull));
    if (flg) wlist[off[blockIdx.x] + pre] = n;
}

__global__ __launch_bounds__(256) void k_T(const float* __restrict__ w,
                                           float* __restrict__ wT) {
    __shared__ float tile[64][65];
    const int t = threadIdx.x;
    const int kt = blockIdx.x >> 2;
    const int ct = blockIdx.x & 3;
    const int k0 = kt * 64, c0 = ct * 64;
    const int rg = t >> 4, cl = (t & 15) * 4;
#pragma unroll
    for (int i = 0; i < 4; ++i) {
        const int r = rg + i * 16;
        float4 v = *reinterpret_cast<const float4*>(w + (size_t)(k0 + r) * CDIM + c0 + cl);
        tile[r][cl] = v.x; tile[r][cl + 1] = v.y;
        tile[r][cl + 2] = v.z; tile[r][cl + 3] = v.w;
    }
    __syncthreads();
#pragma unroll
    for (int i = 0; i < 4; ++i) {
        const int cr = rg + i * 16;
        float4 o;
        o.x = tile[cl + 0][cr]; o.y = tile[cl + 1][cr];
        o.z = tile[cl + 2][cr]; o.w = tile[cl + 3][cr];
        *reinterpret_cast<float4*>(wT + (size_t)(c0 + cr) * KDIM + k0 + cl) = o;
    }
}

// np-exact full-scan GEMM over compacted flag3 rows (round-14-verified).
#define PW(buf, p) { \
    const int pp_ = (p) < 4095 ? (p) : 4095; \
    const float* ap_ = wT + ((size_t)(pp_ & 255) << 13) + ((pp_ >> 8) << 9) + lane8; \
    buf[0] = *(const float4*)(ap_); \
    buf[1] = *(const float4*)(ap_ + 4); }

#define PZ(buf, p) { \
    const float* zp_ = &zt[(p) & 255][wv8]; \
    buf[0] = *(const float4*)(zp_); \
    buf[1] = *(const float4*)(zp_ + 4); }

#define COMP(wb_, zb_) { \
    const float wr_[8] = {wb_[0].x, wb_[0].y, wb_[0].z, wb_[0].w, \
                          wb_[1].x, wb_[1].y, wb_[1].z, wb_[1].w}; \
    const float zr_[8] = {zb_[0].x, zb_[0].y, zb_[0].z, zb_[0].w, \
                          zb_[1].x, zb_[1].y, zb_[1].z, zb_[1].w}; \
    _Pragma("unroll") \
    for (int r_ = 0; r_ < 8; ++r_) \
        _Pragma("unroll") \
        for (int j_ = 0; j_ < 8; ++j_) \
            acc[r_][j_] = fmaf(zr_[r_], wr_[j_], acc[r_][j_]); }

__global__ __launch_bounds__(256, 4) void k_resolve(
    const float* __restrict__ z, const float* __restrict__ wT,
    const float* __restrict__ A, const float* __restrict__ Cq,
    const int* __restrict__ nf_p, const int* __restrict__ wlist,
    float* __restrict__ idx_f)
{
    __shared__ float zt[CDIM][BNR];
    __shared__ int rows[BNR];

    const int t = threadIdx.x;
    const int blk = blockIdx.x;
    const int nf = nf_p[0];
    const int base = blk * BNR;
    if (base >= nf) return;

    if (t < BNR) {
        const int g = base + t;
        rows[t] = wlist[g < nf ? g : base];
    }
    __syncthreads();

    {
        const int j = t & 31;
        const int c0 = t >> 5;
        const int row = rows[j];
        const float* zp = z + (size_t)(row >> 13) * (CDIM * THW) + (row & (THW - 1));
#pragma unroll
        for (int cc = 0; cc < 32; ++cc) {
            const int c = c0 + cc * 8;
            zt[c][j] = zp[(size_t)c * THW];
        }
    }
    __syncthreads();

    const int lane8 = (t & 63) * 8;
    const int wv8 = (t >> 6) * 8;

    float Ar[8];
#pragma unroll
    for (int r = 0; r < 8; ++r) Ar[r] = A[rows[wv8 + r]];

    float best[8];
    int bidx[8];
#pragma unroll
    for (int r = 0; r < 8; ++r) { best[r] = 3.0e38f; bidx[r] = INT_MAX; }

    float4 wa[2], wb[2], za[2], zb4[2];
    PW(wa, 0); PZ(za, 0);

    for (int kt = 0; kt < 16; ++kt) {
        float acc[8][8];
#pragma unroll
        for (int r = 0; r < 8; ++r)
#pragma unroll
            for (int j = 0; j < 8; ++j) acc[r][j] = 0.f;

        const int pbase = kt * 256;
        for (int c2 = 0; c2 < 256; c2 += 2) {
            PW(wb, pbase + c2 + 1); PZ(zb4, pbase + c2 + 1);
            COMP(wa, za);
            PW(wa, pbase + c2 + 2); PZ(za, pbase + c2 + 2);
            COMP(wb, zb4);
        }

        const float4 cq0 = *reinterpret_cast<const float4*>(Cq + kt * 512 + lane8);
        const float4 cq1 = *reinterpret_cast<const float4*>(Cq + kt * 512 + lane8 + 4);
        const float cv[8] = {cq0.x, cq0.y, cq0.z, cq0.w, cq1.x, cq1.y, cq1.z, cq1.w};
#pragma unroll
        for (int j = 0; j < 8; ++j) {
            const int kg = kt * 512 + lane8 + j;
#pragma unroll
            for (int r = 0; r < 8; ++r) {
                const float dd = __fadd_rn(__fadd_rn(Ar[r], -2.0f * acc[r][j]), cv[j]);
                if (dd < best[r]) { best[r] = dd; bidx[r] = kg; }
            }
        }
    }

#pragma unroll
    for (int m = 1; m < 64; m <<= 1) {
#pragma unroll
        for (int r = 0; r < 8; ++r) {
            const float od = __shfl_xor(best[r], m, 64);
            const int oi = __shfl_xor(bidx[r], m, 64);
            if (od < best[r] || (od == best[r] && oi < bidx[r])) {
                best[r] = od; bidx[r] = oi;
            }
        }
    }
    if ((t & 63) == 0) {
#pragma unroll
        for (int r = 0; r < 8; ++r) {
            const int slot = wv8 + r;
            if (base + slot < nf) idx_f[rows[slot]] = (float)bidx[r];
        }
    }
}

__global__ __launch_bounds__(256, 2) void k_out(
    const float* __restrict__ w, const float* __restrict__ z,
    const float* __restrict__ idx_f, float* __restrict__ out0,
    float* __restrict__ partial)
{
    __shared__ float q[CDIM][BNQ + 1];
    __shared__ int si[BNQ];
    __shared__ float red[256];

    const int t = threadIdx.x;
    const int blk = blockIdx.x;
    const int n0 = blk * BNQ;
    const int b = n0 >> 13;
    const int s0 = n0 & (THW - 1);

    if (t < BNQ) si[t] = (int)idx_f[n0 + t];
    __syncthreads();

    {
        const int c = t;
#pragma unroll 4
        for (int i = 0; i < BNQ; ++i)
            q[c][i] = w[(size_t)si[i] * CDIM + c];
    }
    __syncthreads();

    const int sl = t & 63;
    const int cb = t >> 6;
    float lacc = 0.f;
    const size_t base = (size_t)b * (CDIM * THW) + s0 + sl;
#pragma unroll 4
    for (int j = 0; j < 64; ++j) {
        const int c = cb * 64 + j;
        const float qv = q[c][sl];
        const size_t a = base + (size_t)c * THW;
        const float zv = z[a];
        out0[a] = qv;
        const float d = qv - zv;
        lacc = fmaf(d, d, lacc);
    }
    red[t] = lacc;
    __syncthreads();
    for (int mm = 128; mm > 0; mm >>= 1) {
        if (t < mm) red[t] += red[t + mm];
        __syncthreads();
    }
    if (t == 0) partial[blk] = red[0];
}

__global__ __launch_bounds__(256) void k_loss(const float* __restrict__ partial,
                                              float* __restrict__ out_loss) {
    __shared__ double red[256];
    const int t = threadIdx.x;
    double a = 0.0;
    for (int i = t; i < NROWS / BNQ; i += 256) a += (double)partial[i];
    red[t] = a;
    __syncthreads();
    for (int mm = 128; mm > 0; mm >>= 1) {
        if (t < mm) red[t] += red[t + mm];
        __syncthreads();
    }
    if (t == 0) out_loss[0] = (float)(1.25 * red[0] / 8388608.0);
}

extern "C" void kernel_launch(void* const* d_in, const int* in_sizes, int n_in,
                              void* d_out, int out_size, void* d_ws, size_t ws_size,
                              hipStream_t stream) {
    const float* z = (const float*)d_in[0];
    const float* w = (const float*)d_in[1];
    float* out = (float*)d_out;

    char* ws = (char*)d_ws;
    unsigned short* W1 = (unsigned short*)ws;                // 4 MB
    unsigned short* W2 = (unsigned short*)(ws + 4194304);    // 4 MB
    float* wT = (float*)ws;                                  // reuse post-filter
    float* A = (float*)(ws + 8388608);                       // 128 KB
    float* Cq = (float*)(ws + 8519680);                      // 32 KB
    int* pairs = (int*)(ws + 8552448);                       // 128 KB
    int* flag3 = (int*)(ws + 8683520);                       // 128 KB
    int* cnt64 = (int*)(ws + 8814592);                       // 2 KB
    int* off = (int*)(ws + 8816640);                         // 2 KB
    int* nf = (int*)(ws + 8818688);                          // 64 B
    int* wlist = (int*)(ws + 8818752);                       // 128 KB
    float* partial = (float*)(ws + 8949824);                 // 2 KB
    float* pm1 = (float*)(ws + 8951872);                     // 512 KB
    int* pi1 = (int*)(ws + 9476160);                         // 512 KB
    float* pm2 = (float*)(ws + 10000448);                    // 512 KB
    int* pi2 = (int*)(ws + 10524736);                        // 512 KB
    float* pm3 = (float*)(ws + 11049024);                    // 512 KB

    float* out_zq = out;                 // [B,C,T,H,W] = 8388608
    float* out_loss = out + 8388608;     // scalar
    float* out_idx = out + 8388609;      // [B,T,H,W] = 32768, as float

    k_split<<<KDIM * CDIM / 4 / 256, 256, 0, stream>>>(w, W1, W2);
    k_A<<<NROWS / 256, 256, 0, stream>>>(z, A);
    k_C<<<KDIM / 256, 256, 0, stream>>>(w, Cq);
    k_filter<<<NPAN * 512, 256, 0, stream>>>(z, W1, W2, Cq, pm1, pi1, pm2, pi2, pm3);
    k_merge<<<NROWS / 256, 256, 0, stream>>>(pm1, pi1, pm2, pi2, pm3,
                                             out_idx, pairs, flag3, cnt64);
    k_scan<<<1, 512, 0, stream>>>(cnt64, off, nf);
    k_scatter<<<NROWS / 64, 64, 0, stream>>>(flag3, off, wlist);
    k_T<<<512, 256, 0, stream>>>(w, wT);
    k_pair<<<NROWS / 256, 256, 0, stream>>>(z, w, A, Cq, pairs, out_idx);
    k_resolve<<<NROWS / BNR, 256, 0, stream>>>(z, wT, A, Cq, nf, wlist, out_idx);
    k_out<<<NROWS / BNQ, 256, 0, stream>>>(w, z, out_idx, out_zq, partial);
    k_loss<<<1, 256, 0, stream>>>(partial, out_loss);
}

// Round 17
// 1963.854 us; speedup vs baseline: 1.1536x; 1.1536x over previous
//
#include <hip/hip_runtime.h>
#include <limits.h>

#define CDIM 256
#define KDIM 8192
#define NROWS 32768
#define THW 8192
#define BNQ 64
#define BNR 32       // full-resolve rows per block
#define NPAN 4       // code panels (2048 codes each; W-panel 2MB stays in L2)
#define WSIG 8.0e-5f // certified sigma window

typedef __attribute__((ext_vector_type(8))) short short8v;
typedef __attribute__((ext_vector_type(8))) unsigned short u16x8;
typedef __attribute__((ext_vector_type(4))) float f32x4;
typedef __attribute__((ext_vector_type(4))) unsigned short u16x4;

__device__ __forceinline__ float sq_rn(float a) { return __fmul_rn(a, a); }
__device__ __forceinline__ unsigned short bf16rn(float x) {
    unsigned u = __float_as_uint(x);
    return (unsigned short)((u + 0x7FFFu + ((u >> 16) & 1u)) >> 16);
}
__device__ __forceinline__ float bf16tof(unsigned short h) {
    return __uint_as_float(((unsigned)h) << 16);
}

// merge top-3 quintuple (rank-1 tie -> lower k; fixed order => deterministic)
__device__ __forceinline__ void merge3(float& m1, int& i1, float& m2, int& i2,
                                       float& m3, float om1, int oi1,
                                       float om2, int oi2, float om3) {
    if (om1 < m1 || (om1 == m1 && oi1 < i1)) {
        float n2; int n2i;
        if (m1 < om2 || (m1 == om2 && i1 < oi2)) { n2 = m1; n2i = i1; m3 = fminf(m2, om2); }
        else { n2 = om2; n2i = oi2; m3 = fminf(m1, om3); }
        m2 = n2; i2 = n2i; m1 = om1; i1 = oi1;
    } else {
        if (om1 < m2 || (om1 == m2 && oi1 < i2)) { m3 = fminf(m2, om2); m2 = om1; i2 = oi1; }
        else { m3 = fminf(m3, om1); }
    }
}

// numpy pairwise sum of 128 fp32 squares, AVX512 model (verified round 3).
__device__ float pairwise128_sq(const float* __restrict__ p, int stride) {
    float s[16];
#pragma unroll
    for (int l = 0; l < 16; ++l) {
        const float a0 = sq_rn(p[(l)*stride]);
        const float a1 = sq_rn(p[(16 + l) * stride]);
        const float a2 = sq_rn(p[(32 + l) * stride]);
        const float a3 = sq_rn(p[(48 + l) * stride]);
        const float a4 = sq_rn(p[(64 + l) * stride]);
        const float a5 = sq_rn(p[(80 + l) * stride]);
        const float a6 = sq_rn(p[(96 + l) * stride]);
        const float a7 = sq_rn(p[(112 + l) * stride]);
        s[l] = __fadd_rn(__fadd_rn(__fadd_rn(a0, a1), __fadd_rn(a2, a3)),
                         __fadd_rn(__fadd_rn(a4, a5), __fadd_rn(a6, a7)));
    }
    const float u0 = __fadd_rn(__fadd_rn(s[0], s[8]),  __fadd_rn(s[4], s[12]));
    const float u1 = __fadd_rn(__fadd_rn(s[1], s[9]),  __fadd_rn(s[5], s[13]));
    const float u2 = __fadd_rn(__fadd_rn(s[2], s[10]), __fadd_rn(s[6], s[14]));
    const float u3 = __fadd_rn(__fadd_rn(s[3], s[11]), __fadd_rn(s[7], s[15]));
    return __fadd_rn(__fadd_rn(u0, u2), __fadd_rn(u1, u3));
}

__global__ __launch_bounds__(256) void k_A(const float* __restrict__ z,
                                           float* __restrict__ A) {
    const int n = blockIdx.x * 256 + threadIdx.x;
    const float* zp = z + (size_t)(n >> 13) * (CDIM * THW) + (n & (THW - 1));
    const float b0 = pairwise128_sq(zp, THW);
    const float b1 = pairwise128_sq(zp + (size_t)128 * THW, THW);
    A[n] = __fadd_rn(b0, b1);
}

__global__ __launch_bounds__(256) void k_C(const float* __restrict__ w,
                                           float* __restrict__ Cq) {
    const int k = blockIdx.x * 256 + threadIdx.x;
    const float* wp = w + (size_t)k * CDIM;
    Cq[k] = __fadd_rn(pairwise128_sq(wp, 1), pairwise128_sq(wp + 128, 1));
}

__global__ __launch_bounds__(256) void k_split(const float* __restrict__ w,
                                               unsigned short* __restrict__ W1,
                                               unsigned short* __restrict__ W2) {
    const int i = blockIdx.x * 256 + threadIdx.x;
    float4 v = *reinterpret_cast<const float4*>(w + (size_t)i * 4);
    const float x[4] = {v.x, v.y, v.z, v.w};
    u16x4 h, lo;
#pragma unroll
    for (int q = 0; q < 4; ++q) {
        const unsigned short hh = bf16rn(x[q]);
        h[q] = hh;
        lo[q] = bf16rn(x[q] - bf16tof(hh));
    }
    *reinterpret_cast<u16x4*>(W1 + (size_t)i * 4) = h;
    *reinterpret_cast<u16x4*>(W2 + (size_t)i * 4) = lo;
}

// Panel-tiled MFMA split-bf16 filter. launch_bounds(256,1): NO VGPR cap ->
// acc(64) + top-3 state(80) + frags stay in registers (zero scratch spill;
// round-16's 1.3 GB WRITE_SIZE was spill traffic from the (256,2) cap).
__global__ __launch_bounds__(256, 1) void k_filter(
    const float* __restrict__ z,
    const unsigned short* __restrict__ W1, const unsigned short* __restrict__ W2,
    const float* __restrict__ Cq,
    float* __restrict__ pm1, int* __restrict__ pi1,
    float* __restrict__ pm2, int* __restrict__ pi2, float* __restrict__ pm3)
{
    __shared__ unsigned short Z1t[64 * 256];  // 32 KB swizzled bf16 hi
    __shared__ unsigned short Z2t[64 * 256];  // 32 KB lo
    __shared__ float wm1[4][64], wm2[4][64], wm3[4][64];
    __shared__ int   wi1[4][64], wi2[4][64];

    const int t = threadIdx.x;
    const int blk = blockIdx.x;
    const int p = blk >> 9;          // panel (panel-major => co-resident share)
    const int rtile = blk & 511;     // row tile
    const int n0 = rtile * 64;
    const int b = n0 >> 13;
    const int s0 = n0 & (THW - 1);
    const float* zb = z + (size_t)b * (CDIM * THW) + s0;

    {   // stage + split z: nt loads (bypass caches), vector b128 swizzled writes
        const int lane = t & 63;
        const int cg = t >> 6;
        const float* zcol = zb + lane;
        const int swz = (lane & 31) << 4;
#pragma unroll
        for (int it = 0; it < 8; ++it) {
            const int c0 = cg * 8 + it * 32;
            u16x8 hi, lo;
#pragma unroll
            for (int j = 0; j < 8; ++j) {
                const float v = __builtin_nontemporal_load(zcol + (size_t)(c0 + j) * THW);
                const unsigned short h = bf16rn(v);
                hi[j] = h;
                lo[j] = bf16rn(v - bf16tof(h));
            }
            const int off = lane * 512 + ((c0 * 2) ^ swz);
            *(u16x8*)((char*)Z1t + off) = hi;
            *(u16x8*)((char*)Z2t + off) = lo;
        }
    }
    __syncthreads();

    const int l = t & 63;
    const int wv = t >> 6;
    const int l15 = l & 15;
    const int lg = l >> 4;
    const int stripe = p * 2048 + wv * 512;

    float m1v[4][4], m2v[4][4], m3v[4][4];
    int i1v[4][4], i2v[4][4];
#pragma unroll
    for (int rt = 0; rt < 4; ++rt)
#pragma unroll
        for (int i = 0; i < 4; ++i) {
            m1v[rt][i] = 3.0e38f; m2v[rt][i] = 3.0e38f; m3v[rt][i] = 3.0e38f;
            i1v[rt][i] = INT_MAX; i2v[rt][i] = INT_MAX;
        }

    for (int st = 0; st < 8; ++st) {
        const int kb = stripe + st * 64;
        f32x4 acc[4][4];
#pragma unroll
        for (int rt = 0; rt < 4; ++rt)
#pragma unroll
            for (int ct = 0; ct < 4; ++ct)
                acc[rt][ct] = (f32x4){0.f, 0.f, 0.f, 0.f};

        float cqv[4];
#pragma unroll
        for (int ct = 0; ct < 4; ++ct) cqv[ct] = Cq[kb + ct * 16 + l15];

#pragma unroll
        for (int ks = 0; ks < 8; ++ks) {
            const int cb = ks * 32 + lg * 8;
            short8v a1[4], a2[4], bb1[4], bb2[4];
#pragma unroll
            for (int rt = 0; rt < 4; ++rt) {
                const int n = rt * 16 + l15;
                const int off = n * 512 + ((cb * 2) ^ ((n & 31) << 4));
                a1[rt] = *(const short8v*)((const char*)Z1t + off);
                a2[rt] = *(const short8v*)((const char*)Z2t + off);
            }
#pragma unroll
            for (int ct = 0; ct < 4; ++ct) {
                const size_t wo = (size_t)(kb + ct * 16 + l15) * CDIM + cb;
                bb1[ct] = *reinterpret_cast<const short8v*>(W1 + wo);
                bb2[ct] = *reinterpret_cast<const short8v*>(W2 + wo);
            }
#pragma unroll
            for (int rt = 0; rt < 4; ++rt)
#pragma unroll
                for (int ct = 0; ct < 4; ++ct) {
                    acc[rt][ct] = __builtin_amdgcn_mfma_f32_16x16x32_bf16(a1[rt], bb1[ct], acc[rt][ct], 0, 0, 0);
                    acc[rt][ct] = __builtin_amdgcn_mfma_f32_16x16x32_bf16(a1[rt], bb2[ct], acc[rt][ct], 0, 0, 0);
                    acc[rt][ct] = __builtin_amdgcn_mfma_f32_16x16x32_bf16(a2[rt], bb1[ct], acc[rt][ct], 0, 0, 0);
                }
        }

        // sigma = Cq - 2*dot; running top-3 per row; ct/st ascending = k asc.
#pragma unroll
        for (int rt = 0; rt < 4; ++rt)
#pragma unroll
            for (int i = 0; i < 4; ++i) {
#pragma unroll
                for (int ct = 0; ct < 4; ++ct) {
                    const float sig = fmaf(-2.0f, acc[rt][ct][i], cqv[ct]);
                    const int kg = kb + ct * 16 + l15;
                    if (sig < m3v[rt][i]) {
                        if (sig < m1v[rt][i] || (sig == m1v[rt][i] && kg < i1v[rt][i])) {
                            m3v[rt][i] = m2v[rt][i]; m2v[rt][i] = m1v[rt][i]; i2v[rt][i] = i1v[rt][i];
                            m1v[rt][i] = sig; i1v[rt][i] = kg;
                        } else if (sig < m2v[rt][i]) {
                            m3v[rt][i] = m2v[rt][i]; m2v[rt][i] = sig; i2v[rt][i] = kg;
                        } else {
                            m3v[rt][i] = sig;
                        }
                    }
                }
            }
    }

    // merge across the 16 l15 lanes of each lg group
#pragma unroll
    for (int mm = 1; mm < 16; mm <<= 1) {
#pragma unroll
        for (int rt = 0; rt < 4; ++rt)
#pragma unroll
            for (int i = 0; i < 4; ++i) {
                const float om1 = __shfl_xor(m1v[rt][i], mm, 64);
                const int oi1 = __shfl_xor(i1v[rt][i], mm, 64);
                const float om2 = __shfl_xor(m2v[rt][i], mm, 64);
                const int oi2 = __shfl_xor(i2v[rt][i], mm, 64);
                const float om3 = __shfl_xor(m3v[rt][i], mm, 64);
                merge3(m1v[rt][i], i1v[rt][i], m2v[rt][i], i2v[rt][i], m3v[rt][i],
                       om1, oi1, om2, oi2, om3);
            }
    }
    if (l15 == 0) {
#pragma unroll
        for (int rt = 0; rt < 4; ++rt)
#pragma unroll
            for (int i = 0; i < 4; ++i) {
                const int row = rt * 16 + lg * 4 + i;
                wm1[wv][row] = m1v[rt][i]; wi1[wv][row] = i1v[rt][i];
                wm2[wv][row] = m2v[rt][i]; wi2[wv][row] = i2v[rt][i];
                wm3[wv][row] = m3v[rt][i];
            }
    }
    __syncthreads();

    if (t < 64) {   // merge 4 wave-stripes (ascending k), write panel partials
        float m1 = 3.0e38f, m2 = 3.0e38f, m3 = 3.0e38f;
        int i1 = INT_MAX, i2 = INT_MAX;
#pragma unroll
        for (int v = 0; v < 4; ++v)
            merge3(m1, i1, m2, i2, m3, wm1[v][t], wi1[v][t], wm2[v][t], wi2[v][t], wm3[v][t]);
        const int g = p * NROWS + n0 + t;
        pm1[g] = m1; pi1[g] = i1; pm2[g] = m2; pi2[g] = i2; pm3[g] = m3;
    }
}

// Merge the 4 panel partials per row; emit idx, pair candidate, flag3, counts.
__global__ __launch_bounds__(256) void k_merge(
    const float* __restrict__ pm1, const int* __restrict__ pi1,
    const float* __restrict__ pm2, const int* __restrict__ pi2,
    const float* __restrict__ pm3,
    float* __restrict__ idx_f, int* __restrict__ pairs,
    int* __restrict__ flag3, int* __restrict__ cnt64)
{
    const int n = blockIdx.x * 256 + threadIdx.x;
    float m1 = 3.0e38f, m2 = 3.0e38f, m3 = 3.0e38f;
    int i1 = INT_MAX, i2 = INT_MAX;
#pragma unroll
    for (int p = 0; p < NPAN; ++p) {
        const int g = p * NROWS + n;
        merge3(m1, i1, m2, i2, m3, pm1[g], pi1[g], pm2[g], pi2[g], pm3[g]);
    }
    idx_f[n] = (float)i1;
    const int f3 = (m3 - m1 <= WSIG) ? 1 : 0;
    const int f2 = (!f3 && (m2 - m1 <= WSIG)) ? 1 : 0;
    pairs[n] = f2 ? i2 : -1;
    flag3[n] = f3;
    const unsigned long long msk = __ballot(f3);
    if ((threadIdx.x & 63) == 0) cnt64[n >> 6] = (int)__popcll(msk);
}

// np-exact pair resolve: d for {i1, i2} only (single ascending-c fmaf chain).
__global__ __launch_bounds__(256) void k_pair(
    const float* __restrict__ z, const float* __restrict__ w,
    const float* __restrict__ A, const float* __restrict__ Cq,
    const int* __restrict__ pairs, float* __restrict__ idx_f)
{
    const int n = blockIdx.x * 256 + threadIdx.x;
    const int i2 = pairs[n];
    if (i2 < 0) return;
    const int i1 = (int)idx_f[n];
    const float* zp = z + (size_t)(n >> 13) * (CDIM * THW) + (n & (THW - 1));
    const float An = A[n];
    float ma = 0.f, mb = 0.f;
    const float4* wa = (const float4*)(w + (size_t)i1 * CDIM);
    const float4* wb = (const float4*)(w + (size_t)i2 * CDIM);
#pragma unroll 4
    for (int c4 = 0; c4 < CDIM / 4; ++c4) {
        const float z0 = zp[(size_t)(c4 * 4 + 0) * THW];
        const float z1 = zp[(size_t)(c4 * 4 + 1) * THW];
        const float z2 = zp[(size_t)(c4 * 4 + 2) * THW];
        const float z3 = zp[(size_t)(c4 * 4 + 3) * THW];
        const float4 va = wa[c4], vb = wb[c4];
        ma = fmaf(z0, va.x, ma); ma = fmaf(z1, va.y, ma);
        ma = fmaf(z2, va.z, ma); ma = fmaf(z3, va.w, ma);
        mb = fmaf(z0, vb.x, mb); mb = fmaf(z1, vb.y, mb);
        mb = fmaf(z2, vb.z, mb); mb = fmaf(z3, vb.w, mb);
    }
    const float d1 = __fadd_rn(__fadd_rn(An, -2.0f * ma), Cq[i1]);
    const float d2 = __fadd_rn(__fadd_rn(An, -2.0f * mb), Cq[i2]);
    int win = i1;
    if (d2 < d1 || (d2 == d1 && i2 < i1)) win = i2;
    idx_f[n] = (float)win;
}

__global__ __launch_bounds__(512) void k_scan(const int* __restrict__ cnt64,
                                              int* __restrict__ off,
                                              int* __restrict__ nf) {
    __shared__ int sh[512];
    const int t = threadIdx.x;
    const int c = cnt64[t];
    sh[t] = c;
    __syncthreads();
    for (int o = 1; o < 512; o <<= 1) {
        const int v = (t >= o) ? sh[t - o] : 0;
        __syncthreads();
        sh[t] += v;
        __syncthreads();
    }
    off[t] = sh[t] - c;
    if (t == 511) nf[0] = sh[511];
}

__global__ __launch_bounds__(64) void k_scatter(const int* __restrict__ flag,
                                                const int* __restrict__ off,
                                                int* __restrict__ wlist) {
    const int t = threadIdx.x;
    const int n = blockIdx.x * 64 + t;
    const int flg = flag[n];
    const unsigned long long msk = __ballot(flg);
    const int pre = (int)__popcll(msk & ((1ull << t) - 1ull));
    if (flg) wlist[off[blockIdx.x] + pre] = n;
}

__global__ __launch_bounds__(256) void k_T(const float* __restrict__ w,
                                           float* __restrict__ wT) {
    __shared__ float tile[64][65];
    const int t = threadIdx.x;
    const int kt = blockIdx.x >> 2;
    const int ct = blockIdx.x & 3;
    const int k0 = kt * 64, c0 = ct * 64;
    const int rg = t >> 4, cl = (t & 15) * 4;
#pragma unroll
    for (int i = 0; i < 4; ++i) {
        const int r = rg + i * 16;
        float4 v = *reinterpret_cast<const float4*>(w + (size_t)(k0 + r) * CDIM + c0 + cl);
        tile[r][cl] = v.x; tile[r][cl + 1] = v.y;
        tile[r][cl + 2] = v.z; tile[r][cl + 3] = v.w;
    }
    __syncthreads();
#pragma unroll
    for (int i = 0; i < 4; ++i) {
        const int cr = rg + i * 16;
        float4 o;
        o.x = tile[cl + 0][cr]; o.y = tile[cl + 1][cr];
        o.z = tile[cl + 2][cr]; o.w = tile[cl + 3][cr];
        *reinterpret_cast<float4*>(wT + (size_t)(c0 + cr) * KDIM + k0 + cl) = o;
    }
}

// np-exact full-scan GEMM over compacted flag3 rows (round-14-verified).
#define PW(buf, p) { \
    const int pp_ = (p) < 4095 ? (p) : 4095; \
    const float* ap_ = wT + ((size_t)(pp_ & 255) << 13) + ((pp_ >> 8) << 9) + lane8; \
    buf[0] = *(const float4*)(ap_); \
    buf[1] = *(const float4*)(ap_ + 4); }

#define PZ(buf, p) { \
    const float* zp_ = &zt[(p) & 255][wv8]; \
    buf[0] = *(const float4*)(zp_); \
    buf[1] = *(const float4*)(zp_ + 4); }

#define COMP(wb_, zb_) { \
    const float wr_[8] = {wb_[0].x, wb_[0].y, wb_[0].z, wb_[0].w, \
                          wb_[1].x, wb_[1].y, wb_[1].z, wb_[1].w}; \
    const float zr_[8] = {zb_[0].x, zb_[0].y, zb_[0].z, zb_[0].w, \
                          zb_[1].x, zb_[1].y, zb_[1].z, zb_[1].w}; \
    _Pragma("unroll") \
    for (int r_ = 0; r_ < 8; ++r_) \
        _Pragma("unroll") \
        for (int j_ = 0; j_ < 8; ++j_) \
            acc[r_][j_] = fmaf(zr_[r_], wr_[j_], acc[r_][j_]); }

__global__ __launch_bounds__(256, 4) void k_resolve(
    const float* __restrict__ z, const float* __restrict__ wT,
    const float* __restrict__ A, const float* __restrict__ Cq,
    const int* __restrict__ nf_p, const int* __restrict__ wlist,
    float* __restrict__ idx_f)
{
    __shared__ float zt[CDIM][BNR];
    __shared__ int rows[BNR];

    const int t = threadIdx.x;
    const int blk = blockIdx.x;
    const int nf = nf_p[0];
    const int base = blk * BNR;
    if (base >= nf) return;

    if (t < BNR) {
        const int g = base + t;
        rows[t] = wlist[g < nf ? g : base];
    }
    __syncthreads();

    {
        const int j = t & 31;
        const int c0 = t >> 5;
        const int row = rows[j];
        const float* zp = z + (size_t)(row >> 13) * (CDIM * THW) + (row & (THW - 1));
#pragma unroll
        for (int cc = 0; cc < 32; ++cc) {
            const int c = c0 + cc * 8;
            zt[c][j] = zp[(size_t)c * THW];
        }
    }
    __syncthreads();

    const int lane8 = (t & 63) * 8;
    const int wv8 = (t >> 6) * 8;

    float Ar[8];
#pragma unroll
    for (int r = 0; r < 8; ++r) Ar[r] = A[rows[wv8 + r]];

    float best[8];
    int bidx[8];
#pragma unroll
    for (int r = 0; r < 8; ++r) { best[r] = 3.0e38f; bidx[r] = INT_MAX; }

    float4 wa[2], wb[2], za[2], zb4[2];
    PW(wa, 0); PZ(za, 0);

    for (int kt = 0; kt < 16; ++kt) {
        float acc[8][8];
#pragma unroll
        for (int r = 0; r < 8; ++r)
#pragma unroll
            for (int j = 0; j < 8; ++j) acc[r][j] = 0.f;

        const int pbase = kt * 256;
        for (int c2 = 0; c2 < 256; c2 += 2) {
            PW(wb, pbase + c2 + 1); PZ(zb4, pbase + c2 + 1);
            COMP(wa, za);
            PW(wa, pbase + c2 + 2); PZ(za, pbase + c2 + 2);
            COMP(wb, zb4);
        }

        const float4 cq0 = *reinterpret_cast<const float4*>(Cq + kt * 512 + lane8);
        const float4 cq1 = *reinterpret_cast<const float4*>(Cq + kt * 512 + lane8 + 4);
        const float cv[8] = {cq0.x, cq0.y, cq0.z, cq0.w, cq1.x, cq1.y, cq1.z, cq1.w};
#pragma unroll
        for (int j = 0; j < 8; ++j) {
            const int kg = kt * 512 + lane8 + j;
#pragma unroll
            for (int r = 0; r < 8; ++r) {
                const float dd = __fadd_rn(__fadd_rn(Ar[r], -2.0f * acc[r][j]), cv[j]);
                if (dd < best[r]) { best[r] = dd; bidx[r] = kg; }
            }
        }
    }

#pragma unroll
    for (int m = 1; m < 64; m <<= 1) {
#pragma unroll
        for (int r = 0; r < 8; ++r) {
            const float od = __shfl_xor(best[r], m, 64);
            const int oi = __shfl_xor(bidx[r], m, 64);
            if (od < best[r] || (od == best[r] && oi < bidx[r])) {
                best[r] = od; bidx[r] = oi;
            }
        }
    }
    if ((t & 63) == 0) {
#pragma unroll
        for (int r = 0; r < 8; ++r) {
            const int slot = wv8 + r;
            if (base + slot < nf) idx_f[rows[slot]] = (float)bidx[r];
        }
    }
}

__global__ __launch_bounds__(256, 2) void k_out(
    const float* __restrict__ w, const float* __restrict__ z,
    const float* __restrict__ idx_f, float* __restrict__ out0,
    float* __restrict__ partial)
{
    __shared__ float q[CDIM][BNQ + 1];
    __shared__ int si[BNQ];
    __shared__ float red[256];

    const int t = threadIdx.x;
    const int blk = blockIdx.x;
    const int n0 = blk * BNQ;
    const int b = n0 >> 13;
    const int s0 = n0 & (THW - 1);

    if (t < BNQ) si[t] = (int)idx_f[n0 + t];
    __syncthreads();

    {
        const int c = t;
#pragma unroll 4
        for (int i = 0; i < BNQ; ++i)
            q[c][i] = w[(size_t)si[i] * CDIM + c];
    }
    __syncthreads();

    const int sl = t & 63;
    const int cb = t >> 6;
    float lacc = 0.f;
    const size_t base = (size_t)b * (CDIM * THW) + s0 + sl;
#pragma unroll 4
    for (int j = 0; j < 64; ++j) {
        const int c = cb * 64 + j;
        const float qv = q[c][sl];
        const size_t a = base + (size_t)c * THW;
        const float zv = z[a];
        out0[a] = qv;
        const float d = qv - zv;
        lacc = fmaf(d, d, lacc);
    }
    red[t] = lacc;
    __syncthreads();
    for (int mm = 128; mm > 0; mm >>= 1) {
        if (t < mm) red[t] += red[t + mm];
        __syncthreads();
    }
    if (t == 0) partial[blk] = red[0];
}

__global__ __launch_bounds__(256) void k_loss(const float* __restrict__ partial,
                                              float* __restrict__ out_loss) {
    __shared__ double red[256];
    const int t = threadIdx.x;
    double a = 0.0;
    for (int i = t; i < NROWS / BNQ; i += 256) a += (double)partial[i];
    red[t] = a;
    __syncthreads();
    for (int mm = 128; mm > 0; mm >>= 1) {
        if (t < mm) red[t] += red[t + mm];
        __syncthreads();
    }
    if (t == 0) out_loss[0] = (float)(1.25 * red[0] / 8388608.0);
}

extern "C" void kernel_launch(void* const* d_in, const int* in_sizes, int n_in,
                              void* d_out, int out_size, void* d_ws, size_t ws_size,
                              hipStream_t stream) {
    const float* z = (const float*)d_in[0];
    const float* w = (const float*)d_in[1];
    float* out = (float*)d_out;

    char* ws = (char*)d_ws;
    unsigned short* W1 = (unsigned short*)ws;                // 4 MB
    unsigned short* W2 = (unsigned short*)(ws + 4194304);    // 4 MB
    float* wT = (float*)ws;                                  // reuse post-filter
    float* A = (float*)(ws + 8388608);                       // 128 KB
    float* Cq = (float*)(ws + 8519680);                      // 32 KB
    int* pairs = (int*)(ws + 8552448);                       // 128 KB
    int* flag3 = (int*)(ws + 8683520);                       // 128 KB
    int* cnt64 = (int*)(ws + 8814592);                       // 2 KB
    int* off = (int*)(ws + 8816640);                         // 2 KB
    int* nf = (int*)(ws + 8818688);                          // 64 B
    int* wlist = (int*)(ws + 8818752);                       // 128 KB
    float* partial = (float*)(ws + 8949824);                 // 2 KB
    float* pm1 = (float*)(ws + 8951872);                     // 512 KB
    int* pi1 = (int*)(ws + 9476160);                         // 512 KB
    float* pm2 = (float*)(ws + 10000448);                    // 512 KB
    int* pi2 = (int*)(ws + 10524736);                        // 512 KB
    float* pm3 = (float*)(ws + 11049024);                    // 512 KB

    float* out_zq = out;                 // [B,C,T,H,W] = 8388608
    float* out_loss = out + 8388608;     // scalar
    float* out_idx = out + 8388609;      // [B,T,H,W] = 32768, as float

    k_split<<<KDIM * CDIM / 4 / 256, 256, 0, stream>>>(w, W1, W2);
    k_A<<<NROWS / 256, 256, 0, stream>>>(z, A);
    k_C<<<KDIM / 256, 256, 0, stream>>>(w, Cq);
    k_filter<<<NPAN * 512, 256, 0, stream>>>(z, W1, W2, Cq, pm1, pi1, pm2, pi2, pm3);
    k_merge<<<NROWS / 256, 256, 0, stream>>>(pm1, pi1, pm2, pi2, pm3,
                                             out_idx, pairs, flag3, cnt64);
    k_scan<<<1, 512, 0, stream>>>(cnt64, off, nf);
    k_scatter<<<NROWS / 64, 64, 0, stream>>>(flag3, off, wlist);
    k_T<<<512, 256, 0, stream>>>(w, wT);
    k_pair<<<NROWS / 256, 256, 0, stream>>>(z, w, A, Cq, pairs, out_idx);
    k_resolve<<<NROWS / BNR, 256, 0, stream>>>(z, wT, A, Cq, nf, wlist, out_idx);
    k_out<<<NROWS / BNQ, 256, 0, stream>>>(w, z, out_idx, out_zq, partial);
    k_loss<<<1, 256, 0, stream>>>(partial, out_loss);
}

// Round 18
// 1818.178 us; speedup vs baseline: 1.2461x; 1.0801x over previous
//
#include <hip/hip_runtime.h>
#include <limits.h>

#define CDIM 256
#define KDIM 8192
#define NROWS 32768
#define THW 8192
#define BNQ 64
#define BNR 32       // full-resolve rows per block
#define NPAN 4       // code panels (2048 codes each; W-panel 2MB stays in L2)
#define RPT 32       // filter rows per tile (small tile -> 2-3 waves/SIMD)
#define WSIG 8.0e-5f // certified sigma window

typedef __attribute__((ext_vector_type(8))) short short8v;
typedef __attribute__((ext_vector_type(8))) unsigned short u16x8;
typedef __attribute__((ext_vector_type(4))) float f32x4;
typedef __attribute__((ext_vector_type(4))) unsigned short u16x4;

__device__ __forceinline__ float sq_rn(float a) { return __fmul_rn(a, a); }
__device__ __forceinline__ unsigned short bf16rn(float x) {
    unsigned u = __float_as_uint(x);
    return (unsigned short)((u + 0x7FFFu + ((u >> 16) & 1u)) >> 16);
}
__device__ __forceinline__ float bf16tof(unsigned short h) {
    return __uint_as_float(((unsigned)h) << 16);
}

// merge top-3 quintuple (rank-1 tie -> lower k; fixed order => deterministic)
__device__ __forceinline__ void merge3(float& m1, int& i1, float& m2, int& i2,
                                       float& m3, float om1, int oi1,
                                       float om2, int oi2, float om3) {
    if (om1 < m1 || (om1 == m1 && oi1 < i1)) {
        float n2; int n2i;
        if (m1 < om2 || (m1 == om2 && i1 < oi2)) { n2 = m1; n2i = i1; m3 = fminf(m2, om2); }
        else { n2 = om2; n2i = oi2; m3 = fminf(m1, om3); }
        m2 = n2; i2 = n2i; m1 = om1; i1 = oi1;
    } else {
        if (om1 < m2 || (om1 == m2 && oi1 < i2)) { m3 = fminf(m2, om2); m2 = om1; i2 = oi1; }
        else { m3 = fminf(m3, om1); }
    }
}

// numpy pairwise sum of 128 fp32 squares, AVX512 model (verified round 3).
__device__ float pairwise128_sq(const float* __restrict__ p, int stride) {
    float s[16];
#pragma unroll
    for (int l = 0; l < 16; ++l) {
        const float a0 = sq_rn(p[(l)*stride]);
        const float a1 = sq_rn(p[(16 + l) * stride]);
        const float a2 = sq_rn(p[(32 + l) * stride]);
        const float a3 = sq_rn(p[(48 + l) * stride]);
        const float a4 = sq_rn(p[(64 + l) * stride]);
        const float a5 = sq_rn(p[(80 + l) * stride]);
        const float a6 = sq_rn(p[(96 + l) * stride]);
        const float a7 = sq_rn(p[(112 + l) * stride]);
        s[l] = __fadd_rn(__fadd_rn(__fadd_rn(a0, a1), __fadd_rn(a2, a3)),
                         __fadd_rn(__fadd_rn(a4, a5), __fadd_rn(a6, a7)));
    }
    const float u0 = __fadd_rn(__fadd_rn(s[0], s[8]),  __fadd_rn(s[4], s[12]));
    const float u1 = __fadd_rn(__fadd_rn(s[1], s[9]),  __fadd_rn(s[5], s[13]));
    const float u2 = __fadd_rn(__fadd_rn(s[2], s[10]), __fadd_rn(s[6], s[14]));
    const float u3 = __fadd_rn(__fadd_rn(s[3], s[11]), __fadd_rn(s[7], s[15]));
    return __fadd_rn(__fadd_rn(u0, u2), __fadd_rn(u1, u3));
}

__global__ __launch_bounds__(256) void k_A(const float* __restrict__ z,
                                           float* __restrict__ A) {
    const int n = blockIdx.x * 256 + threadIdx.x;
    const float* zp = z + (size_t)(n >> 13) * (CDIM * THW) + (n & (THW - 1));
    const float b0 = pairwise128_sq(zp, THW);
    const float b1 = pairwise128_sq(zp + (size_t)128 * THW, THW);
    A[n] = __fadd_rn(b0, b1);
}

__global__ __launch_bounds__(256) void k_C(const float* __restrict__ w,
                                           float* __restrict__ Cq) {
    const int k = blockIdx.x * 256 + threadIdx.x;
    const float* wp = w + (size_t)k * CDIM;
    Cq[k] = __fadd_rn(pairwise128_sq(wp, 1), pairwise128_sq(wp + 128, 1));
}

__global__ __launch_bounds__(256) void k_split(const float* __restrict__ w,
                                               unsigned short* __restrict__ W1,
                                               unsigned short* __restrict__ W2) {
    const int i = blockIdx.x * 256 + threadIdx.x;
    float4 v = *reinterpret_cast<const float4*>(w + (size_t)i * 4);
    const float x[4] = {v.x, v.y, v.z, v.w};
    u16x4 h, lo;
#pragma unroll
    for (int q = 0; q < 4; ++q) {
        const unsigned short hh = bf16rn(x[q]);
        h[q] = hh;
        lo[q] = bf16rn(x[q] - bf16tof(hh));
    }
    *reinterpret_cast<u16x4*>(W1 + (size_t)i * 4) = h;
    *reinterpret_cast<u16x4*>(W2 + (size_t)i * 4) = lo;
}

// Panel-tiled MFMA split-bf16 filter, 32-row tiles (rt=2, ct=2): small
// register state (acc 16 AGPR + top-3 40 VGPR) -> 2-3 waves/SIMD for
// latency hiding (round-17 was 1 wave/SIMD at 240+64 regs).
__global__ __launch_bounds__(256, 2) void k_filter(
    const float* __restrict__ z,
    const unsigned short* __restrict__ W1, const unsigned short* __restrict__ W2,
    const float* __restrict__ Cq,
    float* __restrict__ pm1, int* __restrict__ pi1,
    float* __restrict__ pm2, int* __restrict__ pi2, float* __restrict__ pm3)
{
    __shared__ unsigned short Z1t[RPT * 256];  // 16 KB swizzled bf16 hi
    __shared__ unsigned short Z2t[RPT * 256];  // 16 KB lo
    __shared__ float wm1[4][RPT], wm2[4][RPT], wm3[4][RPT];
    __shared__ int   wi1[4][RPT], wi2[4][RPT];

    const int t = threadIdx.x;
    const int blk = blockIdx.x;
    const int p = blk >> 10;          // panel (panel-major => co-resident share)
    const int rtile = blk & 1023;     // row tile
    const int n0 = rtile * RPT;
    const int b = n0 >> 13;
    const int s0 = n0 & (THW - 1);
    const float* zb = z + (size_t)b * (CDIM * THW) + s0;

    {   // stage + split z: nt loads, vector b128 swizzled writes
        const int row = t & 31;
        const int cg = t >> 5;        // 8 c-groups
        const float* zcol = zb + row;
        const int swz = (row & 31) << 4;
#pragma unroll
        for (int it = 0; it < 4; ++it) {
            const int c0 = cg * 8 + it * 64;
            u16x8 hi, lo;
#pragma unroll
            for (int j = 0; j < 8; ++j) {
                const float v = __builtin_nontemporal_load(zcol + (size_t)(c0 + j) * THW);
                const unsigned short h = bf16rn(v);
                hi[j] = h;
                lo[j] = bf16rn(v - bf16tof(h));
            }
            const int off = row * 512 + ((c0 * 2) ^ swz);
            *(u16x8*)((char*)Z1t + off) = hi;
            *(u16x8*)((char*)Z2t + off) = lo;
        }
    }
    __syncthreads();

    const int l = t & 63;
    const int wv = t >> 6;
    const int l15 = l & 15;
    const int lg = l >> 4;
    const int stripe = p * 2048 + wv * 512;

    float m1v[2][4], m2v[2][4], m3v[2][4];
    int i1v[2][4], i2v[2][4];
#pragma unroll
    for (int rt = 0; rt < 2; ++rt)
#pragma unroll
        for (int i = 0; i < 4; ++i) {
            m1v[rt][i] = 3.0e38f; m2v[rt][i] = 3.0e38f; m3v[rt][i] = 3.0e38f;
            i1v[rt][i] = INT_MAX; i2v[rt][i] = INT_MAX;
        }

    for (int st = 0; st < 16; ++st) {
        const int kb = stripe + st * 32;
        f32x4 acc[2][2];
#pragma unroll
        for (int rt = 0; rt < 2; ++rt)
#pragma unroll
            for (int ct = 0; ct < 2; ++ct)
                acc[rt][ct] = (f32x4){0.f, 0.f, 0.f, 0.f};

        float cqv[2];
#pragma unroll
        for (int ct = 0; ct < 2; ++ct) cqv[ct] = Cq[kb + ct * 16 + l15];

#pragma unroll
        for (int ks = 0; ks < 8; ++ks) {
            const int cb = ks * 32 + lg * 8;
            short8v a1[2], a2[2], bb1[2], bb2[2];
#pragma unroll
            for (int rt = 0; rt < 2; ++rt) {
                const int n = rt * 16 + l15;
                const int off = n * 512 + ((cb * 2) ^ ((n & 31) << 4));
                a1[rt] = *(const short8v*)((const char*)Z1t + off);
                a2[rt] = *(const short8v*)((const char*)Z2t + off);
            }
#pragma unroll
            for (int ct = 0; ct < 2; ++ct) {
                const size_t wo = (size_t)(kb + ct * 16 + l15) * CDIM + cb;
                bb1[ct] = *reinterpret_cast<const short8v*>(W1 + wo);
                bb2[ct] = *reinterpret_cast<const short8v*>(W2 + wo);
            }
#pragma unroll
            for (int rt = 0; rt < 2; ++rt)
#pragma unroll
                for (int ct = 0; ct < 2; ++ct) {
                    acc[rt][ct] = __builtin_amdgcn_mfma_f32_16x16x32_bf16(a1[rt], bb1[ct], acc[rt][ct], 0, 0, 0);
                    acc[rt][ct] = __builtin_amdgcn_mfma_f32_16x16x32_bf16(a1[rt], bb2[ct], acc[rt][ct], 0, 0, 0);
                    acc[rt][ct] = __builtin_amdgcn_mfma_f32_16x16x32_bf16(a2[rt], bb1[ct], acc[rt][ct], 0, 0, 0);
                }
        }

        // sigma = Cq - 2*dot; running top-3 per row; ct/st ascending = k asc.
#pragma unroll
        for (int rt = 0; rt < 2; ++rt)
#pragma unroll
            for (int i = 0; i < 4; ++i) {
#pragma unroll
                for (int ct = 0; ct < 2; ++ct) {
                    const float sig = fmaf(-2.0f, acc[rt][ct][i], cqv[ct]);
                    const int kg = kb + ct * 16 + l15;
                    if (sig < m3v[rt][i]) {
                        if (sig < m1v[rt][i] || (sig == m1v[rt][i] && kg < i1v[rt][i])) {
                            m3v[rt][i] = m2v[rt][i]; m2v[rt][i] = m1v[rt][i]; i2v[rt][i] = i1v[rt][i];
                            m1v[rt][i] = sig; i1v[rt][i] = kg;
                        } else if (sig < m2v[rt][i]) {
                            m3v[rt][i] = m2v[rt][i]; m2v[rt][i] = sig; i2v[rt][i] = kg;
                        } else {
                            m3v[rt][i] = sig;
                        }
                    }
                }
            }
    }

    // merge across the 16 l15 lanes of each lg group
#pragma unroll
    for (int mm = 1; mm < 16; mm <<= 1) {
#pragma unroll
        for (int rt = 0; rt < 2; ++rt)
#pragma unroll
            for (int i = 0; i < 4; ++i) {
                const float om1 = __shfl_xor(m1v[rt][i], mm, 64);
                const int oi1 = __shfl_xor(i1v[rt][i], mm, 64);
                const float om2 = __shfl_xor(m2v[rt][i], mm, 64);
                const int oi2 = __shfl_xor(i2v[rt][i], mm, 64);
                const float om3 = __shfl_xor(m3v[rt][i], mm, 64);
                merge3(m1v[rt][i], i1v[rt][i], m2v[rt][i], i2v[rt][i], m3v[rt][i],
                       om1, oi1, om2, oi2, om3);
            }
    }
    if (l15 == 0) {
#pragma unroll
        for (int rt = 0; rt < 2; ++rt)
#pragma unroll
            for (int i = 0; i < 4; ++i) {
                const int row = rt * 16 + lg * 4 + i;
                wm1[wv][row] = m1v[rt][i]; wi1[wv][row] = i1v[rt][i];
                wm2[wv][row] = m2v[rt][i]; wi2[wv][row] = i2v[rt][i];
                wm3[wv][row] = m3v[rt][i];
            }
    }
    __syncthreads();

    if (t < RPT) {   // merge 4 wave-stripes (ascending k), write panel partials
        float m1 = 3.0e38f, m2 = 3.0e38f, m3 = 3.0e38f;
        int i1 = INT_MAX, i2 = INT_MAX;
#pragma unroll
        for (int v = 0; v < 4; ++v)
            merge3(m1, i1, m2, i2, m3, wm1[v][t], wi1[v][t], wm2[v][t], wi2[v][t], wm3[v][t]);
        const int g = p * NROWS + n0 + t;
        pm1[g] = m1; pi1[g] = i1; pm2[g] = m2; pi2[g] = i2; pm3[g] = m3;
    }
}

// Merge the 4 panel partials per row; emit idx, pair candidate, flag3, counts.
__global__ __launch_bounds__(256) void k_merge(
    const float* __restrict__ pm1, const int* __restrict__ pi1,
    const float* __restrict__ pm2, const int* __restrict__ pi2,
    const float* __restrict__ pm3,
    float* __restrict__ idx_f, int* __restrict__ pairs,
    int* __restrict__ flag3, int* __restrict__ cnt64)
{
    const int n = blockIdx.x * 256 + threadIdx.x;
    float m1 = 3.0e38f, m2 = 3.0e38f, m3 = 3.0e38f;
    int i1 = INT_MAX, i2 = INT_MAX;
#pragma unroll
    for (int p = 0; p < NPAN; ++p) {
        const int g = p * NROWS + n;
        merge3(m1, i1, m2, i2, m3, pm1[g], pi1[g], pm2[g], pi2[g], pm3[g]);
    }
    idx_f[n] = (float)i1;
    const int f3 = (m3 - m1 <= WSIG) ? 1 : 0;
    const int f2 = (!f3 && (m2 - m1 <= WSIG)) ? 1 : 0;
    pairs[n] = f2 ? i2 : -1;
    flag3[n] = f3;
    const unsigned long long msk = __ballot(f3);
    if ((threadIdx.x & 63) == 0) cnt64[n >> 6] = (int)__popcll(msk);
}

// np-exact pair resolve: d for {i1, i2} only (single ascending-c fmaf chain).
__global__ __launch_bounds__(256) void k_pair(
    const float* __restrict__ z, const float* __restrict__ w,
    const float* __restrict__ A, const float* __restrict__ Cq,
    const int* __restrict__ pairs, float* __restrict__ idx_f)
{
    const int n = blockIdx.x * 256 + threadIdx.x;
    const int i2 = pairs[n];
    if (i2 < 0) return;
    const int i1 = (int)idx_f[n];
    const float* zp = z + (size_t)(n >> 13) * (CDIM * THW) + (n & (THW - 1));
    const float An = A[n];
    float ma = 0.f, mb = 0.f;
    const float4* wa = (const float4*)(w + (size_t)i1 * CDIM);
    const float4* wb = (const float4*)(w + (size_t)i2 * CDIM);
#pragma unroll 4
    for (int c4 = 0; c4 < CDIM / 4; ++c4) {
        const float z0 = zp[(size_t)(c4 * 4 + 0) * THW];
        const float z1 = zp[(size_t)(c4 * 4 + 1) * THW];
        const float z2 = zp[(size_t)(c4 * 4 + 2) * THW];
        const float z3 = zp[(size_t)(c4 * 4 + 3) * THW];
        const float4 va = wa[c4], vb = wb[c4];
        ma = fmaf(z0, va.x, ma); ma = fmaf(z1, va.y, ma);
        ma = fmaf(z2, va.z, ma); ma = fmaf(z3, va.w, ma);
        mb = fmaf(z0, vb.x, mb); mb = fmaf(z1, vb.y, mb);
        mb = fmaf(z2, vb.z, mb); mb = fmaf(z3, vb.w, mb);
    }
    const float d1 = __fadd_rn(__fadd_rn(An, -2.0f * ma), Cq[i1]);
    const float d2 = __fadd_rn(__fadd_rn(An, -2.0f * mb), Cq[i2]);
    int win = i1;
    if (d2 < d1 || (d2 == d1 && i2 < i1)) win = i2;
    idx_f[n] = (float)win;
}

__global__ __launch_bounds__(512) void k_scan(const int* __restrict__ cnt64,
                                              int* __restrict__ off,
                                              int* __restrict__ nf) {
    __shared__ int sh[512];
    const int t = threadIdx.x;
    const int c = cnt64[t];
    sh[t] = c;
    __syncthreads();
    for (int o = 1; o < 512; o <<= 1) {
        const int v = (t >= o) ? sh[t - o] : 0;
        __syncthreads();
        sh[t] += v;
        __syncthreads();
    }
    off[t] = sh[t] - c;
    if (t == 511) nf[0] = sh[511];
}

__global__ __launch_bounds__(64) void k_scatter(const int* __restrict__ flag,
                                                const int* __restrict__ off,
                                                int* __restrict__ wlist) {
    const int t = threadIdx.x;
    const int n = blockIdx.x * 64 + t;
    const int flg = flag[n];
    const unsigned long long msk = __ballot(flg);
    const int pre = (int)__popcll(msk & ((1ull << t) - 1ull));
    if (flg) wlist[off[blockIdx.x] + pre] = n;
}

__global__ __launch_bounds__(256) void k_T(const float* __restrict__ w,
                                           float* __restrict__ wT) {
    __shared__ float tile[64][65];
    const int t = threadIdx.x;
    const int kt = blockIdx.x >> 2;
    const int ct = blockIdx.x & 3;
    const int k0 = kt * 64, c0 = ct * 64;
    const int rg = t >> 4, cl = (t & 15) * 4;
#pragma unroll
    for (int i = 0; i < 4; ++i) {
        const int r = rg + i * 16;
        float4 v = *reinterpret_cast<const float4*>(w + (size_t)(k0 + r) * CDIM + c0 + cl);
        tile[r][cl] = v.x; tile[r][cl + 1] = v.y;
        tile[r][cl + 2] = v.z; tile[r][cl + 3] = v.w;
    }
    __syncthreads();
#pragma unroll
    for (int i = 0; i < 4; ++i) {
        const int cr = rg + i * 16;
        float4 o;
        o.x = tile[cl + 0][cr]; o.y = tile[cl + 1][cr];
        o.z = tile[cl + 2][cr]; o.w = tile[cl + 3][cr];
        *reinterpret_cast<float4*>(wT + (size_t)(c0 + cr) * KDIM + k0 + cl) = o;
    }
}

// np-exact full-scan GEMM over compacted flag3 rows (round-14-verified).
#define PW(buf, p) { \
    const int pp_ = (p) < 4095 ? (p) : 4095; \
    const float* ap_ = wT + ((size_t)(pp_ & 255) << 13) + ((pp_ >> 8) << 9) + lane8; \
    buf[0] = *(const float4*)(ap_); \
    buf[1] = *(const float4*)(ap_ + 4); }

#define PZ(buf, p) { \
    const float* zp_ = &zt[(p) & 255][wv8]; \
    buf[0] = *(const float4*)(zp_); \
    buf[1] = *(const float4*)(zp_ + 4); }

#define COMP(wb_, zb_) { \
    const float wr_[8] = {wb_[0].x, wb_[0].y, wb_[0].z, wb_[0].w, \
                          wb_[1].x, wb_[1].y, wb_[1].z, wb_[1].w}; \
    const float zr_[8] = {zb_[0].x, zb_[0].y, zb_[0].z, zb_[0].w, \
                          zb_[1].x, zb_[1].y, zb_[1].z, zb_[1].w}; \
    _Pragma("unroll") \
    for (int r_ = 0; r_ < 8; ++r_) \
        _Pragma("unroll") \
        for (int j_ = 0; j_ < 8; ++j_) \
            acc[r_][j_] = fmaf(zr_[r_], wr_[j_], acc[r_][j_]); }

__global__ __launch_bounds__(256, 4) void k_resolve(
    const float* __restrict__ z, const float* __restrict__ wT,
    const float* __restrict__ A, const float* __restrict__ Cq,
    const int* __restrict__ nf_p, const int* __restrict__ wlist,
    float* __restrict__ idx_f)
{
    __shared__ float zt[CDIM][BNR];
    __shared__ int rows[BNR];

    const int t = threadIdx.x;
    const int blk = blockIdx.x;
    const int nf = nf_p[0];
    const int base = blk * BNR;
    if (base >= nf) return;

    if (t < BNR) {
        const int g = base + t;
        rows[t] = wlist[g < nf ? g : base];
    }
    __syncthreads();

    {
        const int j = t & 31;
        const int c0 = t >> 5;
        const int row = rows[j];
        const float* zp = z + (size_t)(row >> 13) * (CDIM * THW) + (row & (THW - 1));
#pragma unroll
        for (int cc = 0; cc < 32; ++cc) {
            const int c = c0 + cc * 8;
            zt[c][j] = zp[(size_t)c * THW];
        }
    }
    __syncthreads();

    const int lane8 = (t & 63) * 8;
    const int wv8 = (t >> 6) * 8;

    float Ar[8];
#pragma unroll
    for (int r = 0; r < 8; ++r) Ar[r] = A[rows[wv8 + r]];

    float best[8];
    int bidx[8];
#pragma unroll
    for (int r = 0; r < 8; ++r) { best[r] = 3.0e38f; bidx[r] = INT_MAX; }

    float4 wa[2], wb[2], za[2], zb4[2];
    PW(wa, 0); PZ(za, 0);

    for (int kt = 0; kt < 16; ++kt) {
        float acc[8][8];
#pragma unroll
        for (int r = 0; r < 8; ++r)
#pragma unroll
            for (int j = 0; j < 8; ++j) acc[r][j] = 0.f;

        const int pbase = kt * 256;
        for (int c2 = 0; c2 < 256; c2 += 2) {
            PW(wb, pbase + c2 + 1); PZ(zb4, pbase + c2 + 1);
            COMP(wa, za);
            PW(wa, pbase + c2 + 2); PZ(za, pbase + c2 + 2);
            COMP(wb, zb4);
        }

        const float4 cq0 = *reinterpret_cast<const float4*>(Cq + kt * 512 + lane8);
        const float4 cq1 = *reinterpret_cast<const float4*>(Cq + kt * 512 + lane8 + 4);
        const float cv[8] = {cq0.x, cq0.y, cq0.z, cq0.w, cq1.x, cq1.y, cq1.z, cq1.w};
#pragma unroll
        for (int j = 0; j < 8; ++j) {
            const int kg = kt * 512 + lane8 + j;
#pragma unroll
            for (int r = 0; r < 8; ++r) {
                const float dd = __fadd_rn(__fadd_rn(Ar[r], -2.0f * acc[r][j]), cv[j]);
                if (dd < best[r]) { best[r] = dd; bidx[r] = kg; }
            }
        }
    }

#pragma unroll
    for (int m = 1; m < 64; m <<= 1) {
#pragma unroll
        for (int r = 0; r < 8; ++r) {
            const float od = __shfl_xor(best[r], m, 64);
            const int oi = __shfl_xor(bidx[r], m, 64);
            if (od < best[r] || (od == best[r] && oi < bidx[r])) {
                best[r] = od; bidx[r] = oi;
            }
        }
    }
    if ((t & 63) == 0) {
#pragma unroll
        for (int r = 0; r < 8; ++r) {
            const int slot = wv8 + r;
            if (base + slot < nf) idx_f[rows[slot]] = (float)bidx[r];
        }
    }
}

__global__ __launch_bounds__(256, 2) void k_out(
    const float* __restrict__ w, const float* __restrict__ z,
    const float* __restrict__ idx_f, float* __restrict__ out0,
    float* __restrict__ partial)
{
    __shared__ float q[CDIM][BNQ + 1];
    __shared__ int si[BNQ];
    __shared__ float red[256];

    const int t = threadIdx.x;
    const int blk = blockIdx.x;
    const int n0 = blk * BNQ;
    const int b = n0 >> 13;
    const int s0 = n0 & (THW - 1);

    if (t < BNQ) si[t] = (int)idx_f[n0 + t];
    __syncthreads();

    {
        const int c = t;
#pragma unroll 4
        for (int i = 0; i < BNQ; ++i)
            q[c][i] = w[(size_t)si[i] * CDIM + c];
    }
    __syncthreads();

    const int sl = t & 63;
    const int cb = t >> 6;
    float lacc = 0.f;
    const size_t base = (size_t)b * (CDIM * THW) + s0 + sl;
#pragma unroll 4
    for (int j = 0; j < 64; ++j) {
        const int c = cb * 64 + j;
        const float qv = q[c][sl];
        const size_t a = base + (size_t)c * THW;
        const float zv = z[a];
        out0[a] = qv;
        const float d = qv - zv;
        lacc = fmaf(d, d, lacc);
    }
    red[t] = lacc;
    __syncthreads();
    for (int mm = 128; mm > 0; mm >>= 1) {
        if (t < mm) red[t] += red[t + mm];
        __syncthreads();
    }
    if (t == 0) partial[blk] = red[0];
}

__global__ __launch_bounds__(256) void k_loss(const float* __restrict__ partial,
                                              float* __restrict__ out_loss) {
    __shared__ double red[256];
    const int t = threadIdx.x;
    double a = 0.0;
    for (int i = t; i < NROWS / BNQ; i += 256) a += (double)partial[i];
    red[t] = a;
    __syncthreads();
    for (int mm = 128; mm > 0; mm >>= 1) {
        if (t < mm) red[t] += red[t + mm];
        __syncthreads();
    }
    if (t == 0) out_loss[0] = (float)(1.25 * red[0] / 8388608.0);
}

extern "C" void kernel_launch(void* const* d_in, const int* in_sizes, int n_in,
                              void* d_out, int out_size, void* d_ws, size_t ws_size,
                              hipStream_t stream) {
    const float* z = (const float*)d_in[0];
    const float* w = (const float*)d_in[1];
    float* out = (float*)d_out;

    char* ws = (char*)d_ws;
    unsigned short* W1 = (unsigned short*)ws;                // 4 MB
    unsigned short* W2 = (unsigned short*)(ws + 4194304);    // 4 MB
    float* wT = (float*)ws;                                  // reuse post-filter
    float* A = (float*)(ws + 8388608);                       // 128 KB
    float* Cq = (float*)(ws + 8519680);                      // 32 KB
    int* pairs = (int*)(ws + 8552448);                       // 128 KB
    int* flag3 = (int*)(ws + 8683520);                       // 128 KB
    int* cnt64 = (int*)(ws + 8814592);                       // 2 KB
    int* off = (int*)(ws + 8816640);                         // 2 KB
    int* nf = (int*)(ws + 8818688);                          // 64 B
    int* wlist = (int*)(ws + 8818752);                       // 128 KB
    float* partial = (float*)(ws + 8949824);                 // 2 KB
    float* pm1 = (float*)(ws + 8951872);                     // 512 KB
    int* pi1 = (int*)(ws + 9476160);                         // 512 KB
    float* pm2 = (float*)(ws + 10000448);                    // 512 KB
    int* pi2 = (int*)(ws + 10524736);                        // 512 KB
    float* pm3 = (float*)(ws + 11049024);                    // 512 KB

    float* out_zq = out;                 // [B,C,T,H,W] = 8388608
    float* out_loss = out + 8388608;     // scalar
    float* out_idx = out + 8388609;      // [B,T,H,W] = 32768, as float

    k_split<<<KDIM * CDIM / 4 / 256, 256, 0, stream>>>(w, W1, W2);
    k_A<<<NROWS / 256, 256, 0, stream>>>(z, A);
    k_C<<<KDIM / 256, 256, 0, stream>>>(w, Cq);
    k_filter<<<NPAN * (NROWS / RPT), 256, 0, stream>>>(z, W1, W2, Cq, pm1, pi1, pm2, pi2, pm3);
    k_merge<<<NROWS / 256, 256, 0, stream>>>(pm1, pi1, pm2, pi2, pm3,
                                             out_idx, pairs, flag3, cnt64);
    k_scan<<<1, 512, 0, stream>>>(cnt64, off, nf);
    k_scatter<<<NROWS / 64, 64, 0, stream>>>(flag3, off, wlist);
    k_T<<<512, 256, 0, stream>>>(w, wT);
    k_pair<<<NROWS / 256, 256, 0, stream>>>(z, w, A, Cq, pairs, out_idx);
    k_resolve<<<NROWS / BNR, 256, 0, stream>>>(z, wT, A, Cq, nf, wlist, out_idx);
    k_out<<<NROWS / BNQ, 256, 0, stream>>>(w, z, out_idx, out_zq, partial);
    k_loss<<<1, 256, 0, stream>>>(partial, out_loss);
}